// Round 12
// baseline (1169.321 us; speedup 1.0000x reference)
//
#include <hip/hip_runtime.h>

// Problem constants
#define NB   64      // batch
#define CIN  8
#define LIN  8192
#define L1N  4096    // conv1 out length
#define T2   2048    // conv2 out length (time steps)
#define ENC  64
#define NK   128     // codebook size
#define CD   64      // code dim
#define G3   192     // 3*ENC

// d_out layout (floats): quant_z [64*2048*64] | pred [64*2048*64] | codes [64*2048]
#define QOFF 0
#define POFF 8388608
#define COFF 16777216

// ws layout (floats): (unused)[128] @0 | PC[128*192] @128 | codes_i[131072] (int) @24704
#define PCOFF 128
#define CIOFF 24704

typedef _Float16 half2v __attribute__((ext_vector_type(2)));

__device__ __forceinline__ float sigf(float x) {
  float e = __builtin_amdgcn_exp2f(-1.4426950408889634f * x);
  return __builtin_amdgcn_rcpf(1.0f + e);
}
__device__ __forceinline__ float tanhf_fast(float x) {
  float e = __builtin_amdgcn_exp2f(2.8853900817779268f * x);
  return 1.0f - 2.0f * __builtin_amdgcn_rcpf(e + 1.0f);
}
__device__ __forceinline__ float rlane(float v, int k) {
  return __int_as_float(__builtin_amdgcn_readlane(__float_as_int(v), k));
}
__device__ __forceinline__ half2v as_h2(float v) { return __builtin_bit_cast(half2v, v); }

// ---------------- K1: FUSED conv1 + conv2 + VQ + (prep: cnorm inline, PC rows in blocks 0..127) ----------------
// R10/R11's proven conv12q with prep_kernel absorbed:
//  - cnorm is computed inline in the quant phase from the already-register-resident codebook
//    rows ca[]/cq[], using prep's exact accumulation expression (bit-identical -> codes exact);
//  - blocks 0..127 additionally compute PC row c=blockIdx.x (prep's exact code, relocated) at
//    the end; gruproj reads PC across the kernel boundary as before.
// Kills one launch + its gap + the cnorm ws round-trip.
__global__ __launch_bounds__(256) void conv12q_kernel(const float* __restrict__ x,
                                                      const float* __restrict__ w1,
                                                      const float* __restrict__ b1,
                                                      const float* __restrict__ w2,
                                                      const float* __restrict__ b2,
                                                      const float* __restrict__ cb,
                                                      const float* __restrict__ w_ih,
                                                      const float* __restrict__ b_ih,
                                                      float* __restrict__ PC,
                                                      float* __restrict__ quant,
                                                      float* __restrict__ codes_f,
                                                      int* __restrict__ codes_i) {
  __shared__ float sw2[32 * 5 * 64];     // 40960 B
  __shared__ float sw1[1280];            //  5120 B
  __shared__ float sy[32][136];          // 17408 B
  __shared__ float ubuf[4096];           // 16384 B : sxx[8][280] (phase A/B) then sz[64][64]
  float (*sxx)[280] = (float(*)[280])ubuf;
  float (*sz)[64]   = (float(*)[64])ubuf;
  int b = blockIdx.x >> 5;
  int t0 = (blockIdx.x & 31) * 64;
  int tid = threadIdx.x;

  // ---- phase A: stage x-tile + conv1 weights + conv2 weights ----
  for (int i = tid; i < 32 * 5 * 64; i += 256) {
    int co = i & 63, r = i >> 6;
    sw2[i] = w2[co * 160 + r];
  }
  for (int i = tid; i < 1280; i += 256) sw1[i] = w1[i];
  {
    const float* xb = x + b * CIN * LIN;
    int X0 = 4 * t0 - 10;
    for (int i = tid; i < 8 * 280; i += 256) {
      int ci = i / 280, xo = i - ci * 280;
      int xi = X0 + xo;
      sxx[ci][xo] = ((unsigned)xi < (unsigned)LIN) ? xb[ci * LIN + xi] : 0.f;
    }
  }
  __syncthreads();

  // ---- phase B: y1 window (conv1+relu), conv1's accumulation order (bias, ci, k) ----
  {
    int co1 = tid >> 3, sub = tid & 7;       // co1 in [0,32), 17 outputs per thread
    float acc1[17];
    float bias = b1[co1];
#pragma unroll
    for (int jj = 0; jj < 17; jj++) acc1[jj] = bias;
#pragma unroll 1
    for (int ci = 0; ci < 8; ci++) {
      float xv[38];
      const float2* s2 = (const float2*)(&sxx[ci][34 * sub]);
#pragma unroll
      for (int q = 0; q < 19; q++) {
        float2 v = s2[q];
        xv[2 * q] = v.x; xv[2 * q + 1] = v.y;
      }
      float wk1[5];
#pragma unroll
      for (int k = 0; k < 5; k++) wk1[k] = sw1[(co1 * 8 + ci) * 5 + k];
#pragma unroll
      for (int jj = 0; jj < 17; jj++) {
#pragma unroll
        for (int k = 0; k < 5; k++) acc1[jj] = fmaf(xv[2 * jj + k], wk1[k], acc1[jj]);
      }
    }
#pragma unroll
    for (int jj = 0; jj < 17; jj++) {
      int u = 17 * sub + jj;
      int p = 2 * t0 - 4 + u;                // y1 position
      sy[co1][u] = ((unsigned)p < (unsigned)L1N) ? fmaxf(acc1[jj], 0.f) : 0.f;
    }
  }
  __syncthreads();                            // sxx dead from here; ubuf becomes sz

  // ---- phase C: conv2 + relu into sz ----
  int co = tid & 63, ts = tid >> 6;
  {
    float acc[16];
    float bb = b2[co];
#pragma unroll
    for (int i = 0; i < 16; i++) acc[i] = bb;
    for (int ci = 0; ci < 32; ci++) {
      float xr[40];
      const float4* sx4 = (const float4*)(&sy[ci][32 * ts]);
#pragma unroll
      for (int q = 0; q < 10; q++) {
        float4 v = sx4[q];
        xr[4 * q] = v.x; xr[4 * q + 1] = v.y; xr[4 * q + 2] = v.z; xr[4 * q + 3] = v.w;
      }
      float wk[5];
#pragma unroll
      for (int k = 0; k < 5; k++) wk[k] = sw2[(ci * 5 + k) * 64 + co];
#pragma unroll
      for (int i = 0; i < 16; i++) {
#pragma unroll
        for (int k = 0; k < 5; k++) acc[i] = fmaf(xr[2 * i + k + 2], wk[k], acc[i]);
      }
    }
#pragma unroll
    for (int i = 0; i < 16; i++) sz[ts * 16 + i][co] = fmaxf(acc[i], 0.f);
  }
  __syncthreads();

  // ---- quant phase (cnorm computed inline, prep's exact expression) ----
  int lane = co, wave = ts;
  float4 ca[16], cq[16];
  {
    const float4* pa = (const float4*)(cb + lane * CD);
    const float4* pb = (const float4*)(cb + (64 + lane) * CD);
#pragma unroll
    for (int q = 0; q < 16; q++) { ca[q] = pa[q]; cq[q] = pb[q]; }
  }
  float cn0, cn1;
  {
    float s0 = 0.f, s1 = 0.f, s2 = 0.f, s3 = 0.f;
#pragma unroll
    for (int q = 0; q < 16; q += 4) {
      float4 a = ca[q], b4 = ca[q + 1], cc = ca[q + 2], d = ca[q + 3];
      s0 += a.x * a.x + a.y * a.y + a.z * a.z + a.w * a.w;
      s1 += b4.x * b4.x + b4.y * b4.y + b4.z * b4.z + b4.w * b4.w;
      s2 += cc.x * cc.x + cc.y * cc.y + cc.z * cc.z + cc.w * cc.w;
      s3 += d.x * d.x + d.y * d.y + d.z * d.z + d.w * d.w;
    }
    cn0 = (s0 + s1) + (s2 + s3);
    s0 = 0.f; s1 = 0.f; s2 = 0.f; s3 = 0.f;
#pragma unroll
    for (int q = 0; q < 16; q += 4) {
      float4 a = cq[q], b4 = cq[q + 1], cc = cq[q + 2], d = cq[q + 3];
      s0 += a.x * a.x + a.y * a.y + a.z * a.z + a.w * a.w;
      s1 += b4.x * b4.x + b4.y * b4.y + b4.z * b4.z + b4.w * b4.w;
      s2 += cc.x * cc.x + cc.y * cc.y + cc.z * cc.z + cc.w * cc.w;
      s3 += d.x * d.x + d.y * d.y + d.z * d.z + d.w * d.w;
    }
    cn1 = (s0 + s1) + (s2 + s3);
  }
  int vg0 = b * T2 + t0 + wave * 16;
  for (int i = 0; i < 16; i++) {
    int vl = wave * 16 + i;
    int v = vg0 + i;
    float d00 = 0.f, d01 = 0.f, d02 = 0.f, d03 = 0.f;
    float d10 = 0.f, d11 = 0.f, d12 = 0.f, d13 = 0.f;
#pragma unroll
    for (int q = 0; q < 16; q++) {
      float4 zq = *(const float4*)(&sz[vl][4 * q]);   // broadcast read, conflict-free
      d00 = fmaf(ca[q].x, zq.x, d00); d01 = fmaf(ca[q].y, zq.y, d01);
      d02 = fmaf(ca[q].z, zq.z, d02); d03 = fmaf(ca[q].w, zq.w, d03);
      d10 = fmaf(cq[q].x, zq.x, d10); d11 = fmaf(cq[q].y, zq.y, d11);
      d12 = fmaf(cq[q].z, zq.z, d12); d13 = fmaf(cq[q].w, zq.w, d13);
    }
    float s0 = cn0 - 2.f * ((d00 + d01) + (d02 + d03));
    float s1 = cn1 - 2.f * ((d10 + d11) + (d12 + d13));
    float sc; int idx;
    if (s1 < s0) { sc = s1; idx = 64 + lane; } else { sc = s0; idx = lane; }
#pragma unroll
    for (int m = 1; m < 64; m <<= 1) {
      float os = __shfl_xor(sc, m);
      int oi = __shfl_xor(idx, m);
      if (os < sc || (os == sc && oi < idx)) { sc = os; idx = oi; }
    }
    if (lane == 0) { codes_f[v] = (float)idx; codes_i[v] = idx; }
    quant[v * 64 + lane] = cb[idx * 64 + lane];
  }

  // ---- prep phase: blocks 0..127 compute PC row c = blockIdx.x (prep's exact code) ----
  if (blockIdx.x < NK && tid < G3) {
    int c = blockIdx.x;
    int j = tid;
    const float4* wp = (const float4*)(w_ih + j * ENC);
    const float4* cp = (const float4*)(cb + c * CD);
    float a0 = b_ih[j], a1 = 0.f, a2 = 0.f, a3 = 0.f;
#pragma unroll
    for (int q = 0; q < 16; q += 4) {
      float4 w0 = wp[q], c0 = cp[q];
      float4 w1v = wp[q + 1], c1 = cp[q + 1];
      float4 w2v = wp[q + 2], c2 = cp[q + 2];
      float4 w3 = wp[q + 3], c3 = cp[q + 3];
      a0 += w0.x * c0.x + w0.y * c0.y + w0.z * c0.z + w0.w * c0.w;
      a1 += w1v.x * c1.x + w1v.y * c1.y + w1v.z * c1.z + w1v.w * c1.w;
      a2 += w2v.x * c2.x + w2v.y * c2.y + w2v.z * c2.z + w2v.w * c2.w;
      a3 += w3.x * c3.x + w3.y * c3.y + w3.z * c3.z + w3.w * c3.w;
    }
    PC[c * G3 + j] = (a0 + a1) + (a2 + a3);
  }
}

// ---------------- K5: FUSED GRU scan + projection + wave-1 x-gather (R11, proven 755us) ----------------
__global__ __attribute__((amdgpu_flat_work_group_size(256, 256), amdgpu_waves_per_eu(1, 1)))
void gruproj_kernel(const float* __restrict__ PC,
                    const int* __restrict__ codes_i,
                    const float* __restrict__ w_hh,
                    const float* __restrict__ b_hh,
                    const float* __restrict__ proj_w,
                    const float* __restrict__ proj_b,
                    float* __restrict__ pred) {
  __shared__ float pcl[NK * G3];         // 98304 B
  __shared__ int   cpl[T2];              //  8192 B
  __shared__ float hring[2][16][64];     //  8192 B
  __shared__ float xring[2][16][3][64];  // 24576 B  (total 139264 B)
  int b = blockIdx.x;
  int tid = threadIdx.x;
  int lane = tid & 63;
  int wq = tid >> 6;

  // stage this batch's codes + the PC table with all 256 threads
  {
    const int4* src = (const int4*)(codes_i + b * T2);
    int4* dst = (int4*)cpl;
    for (int f = tid; f < T2 / 4; f += 256) dst[f] = src[f];
    const float4* s2 = (const float4*)PC;
    float4* d2 = (float4*)pcl;
    for (int f = tid; f < NK * G3 / 4; f += 256) d2[f] = s2[f];
  }
  __syncthreads();

  // ---- per-role setup (wave-uniform branch) ----
  half2v wr[32], wz[32], wn[32];
  float br = 0.f, bz = 0.f, bn = 0.f;
  float hreg = 0.f;
  float4 w[16];
  float pbias = 0.f;

  if (wq == 0) {
    const float2* p0 = (const float2*)(w_hh + lane * ENC);
    const float2* p1 = (const float2*)(w_hh + (64 + lane) * ENC);
    const float2* p2 = (const float2*)(w_hh + (128 + lane) * ENC);
#pragma unroll
    for (int m = 0; m < 32; m++) {
      float2 a = p0[m]; wr[m] = (half2v){(_Float16)a.x, (_Float16)a.y};
      float2 c = p1[m]; wz[m] = (half2v){(_Float16)c.x, (_Float16)c.y};
      float2 d = p2[m]; wn[m] = (half2v){(_Float16)d.x, (_Float16)d.y};
    }
    br = b_hh[lane]; bz = b_hh[64 + lane]; bn = b_hh[128 + lane];
  } else {
    const float4* wp = (const float4*)(proj_w + lane * ENC);
#pragma unroll
    for (int q = 0; q < 16; q++) w[q] = wp[q];
    pbias = proj_b[lane];
    if (wq == 1) {
      // prologue: gather x rows for chunk 0 into xring[0]
#pragma unroll 1
      for (int i = 0; i < 16; i++) {
        int code = cpl[i];
        const float* g = pcl + code * G3;
        xring[0][i][0][lane] = g[lane];
        xring[0][i][1][lane] = g[64 + lane];
        xring[0][i][2][lane] = g[128 + lane];
      }
    }
  }
  __syncthreads();   // xring[0] ready for wave 0

  int lane2a = 2 * lane, lane2b = 2 * lane + 1;  // shuffle sources (loop-invariant)
  float* pbase = pred + (size_t)b * T2 * ENC + lane;

#pragma unroll 1
  for (int c = 0; c < 128; c++) {
    if (wq == 0) {
      // ---- 16 GRU steps using xring[c&1], writing h into hring[c&1] ----
      const float* xbuf = &xring[c & 1][0][0][0];
#pragma unroll 1
      for (int i = 0; i < 16; i++) {
        const float* xp = xbuf + i * 192;
        float xr = xp[lane], xz = xp[64 + lane], xn = xp[128 + lane];
        float he = __shfl(hreg, lane2a);
        float ho = __shfl(hreg, lane2b);
        half2v hp2 = {(_Float16)he, (_Float16)ho};
        float hpk = __builtin_bit_cast(float, hp2);
        float fr0 = br, fr1 = 0.f, fr2 = 0.f, fr3 = 0.f;
        float fz0 = bz, fz1 = 0.f, fz2 = 0.f, fz3 = 0.f;
        float fn0 = bn, fn1 = 0.f, fn2 = 0.f, fn3 = 0.f;
#define MV(q) { \
    float s0 = rlane(hpk, 4 * (q) + 0); float s1 = rlane(hpk, 4 * (q) + 1); \
    float s2 = rlane(hpk, 4 * (q) + 2); float s3 = rlane(hpk, 4 * (q) + 3); \
    fr0 = __builtin_amdgcn_fdot2(wr[4 * (q) + 0], as_h2(s0), fr0, false); \
    fr1 = __builtin_amdgcn_fdot2(wr[4 * (q) + 1], as_h2(s1), fr1, false); \
    fr2 = __builtin_amdgcn_fdot2(wr[4 * (q) + 2], as_h2(s2), fr2, false); \
    fr3 = __builtin_amdgcn_fdot2(wr[4 * (q) + 3], as_h2(s3), fr3, false); \
    fz0 = __builtin_amdgcn_fdot2(wz[4 * (q) + 0], as_h2(s0), fz0, false); \
    fz1 = __builtin_amdgcn_fdot2(wz[4 * (q) + 1], as_h2(s1), fz1, false); \
    fz2 = __builtin_amdgcn_fdot2(wz[4 * (q) + 2], as_h2(s2), fz2, false); \
    fz3 = __builtin_amdgcn_fdot2(wz[4 * (q) + 3], as_h2(s3), fz3, false); \
    fn0 = __builtin_amdgcn_fdot2(wn[4 * (q) + 0], as_h2(s0), fn0, false); \
    fn1 = __builtin_amdgcn_fdot2(wn[4 * (q) + 1], as_h2(s1), fn1, false); \
    fn2 = __builtin_amdgcn_fdot2(wn[4 * (q) + 2], as_h2(s2), fn2, false); \
    fn3 = __builtin_amdgcn_fdot2(wn[4 * (q) + 3], as_h2(s3), fn3, false); }
        MV(0) MV(1) MV(2) MV(3) MV(4) MV(5) MV(6) MV(7)
#undef MV
        float ghr = (fr0 + fr1) + (fr2 + fr3);
        float ghz = (fz0 + fz1) + (fz2 + fz3);
        float ghn = (fn0 + fn1) + (fn2 + fn3);
        float r = sigf(xr + ghr);
        float zg = sigf(xz + ghz);
        float n = tanhf_fast(xn + r * ghn);
        hreg = fmaf(zg, hreg - n, n);
        hring[c & 1][i][lane] = hreg;
      }
    } else {
      if (wq == 1 && c < 127) {
        // ---- gather x rows for chunk c+1 into xring[(c+1)&1] ----
        int tbase = (c + 1) * 16;
        float* xb2 = &xring[(c + 1) & 1][0][0][0];
#pragma unroll 1
        for (int i = 0; i < 16; i++) {
          int code = cpl[tbase + i];
          const float* g = pcl + code * G3;
          float* xo = xb2 + i * 192;
          xo[lane] = g[lane];
          xo[64 + lane] = g[64 + lane];
          xo[128 + lane] = g[128 + lane];
        }
      }
      if (c > 0) {
        // ---- project chunk c-1 from hring[(c-1)&1] ----
        int cc = c - 1, buf = cc & 1, tb = cc * 16;
#pragma unroll 1
        for (int t = wq - 1; t < 16; t += 3) {
          const float4* hrow = (const float4*)(&hring[buf][t][0]);   // broadcast reads
          float a0 = pbias, a1 = 0.f, a2 = 0.f, a3 = 0.f;
#pragma unroll
          for (int q = 0; q < 16; q += 4) {
            float4 ha = hrow[q], hb = hrow[q + 1], hc = hrow[q + 2], hd = hrow[q + 3];
            a0 += ha.x * w[q].x + ha.y * w[q].y + ha.z * w[q].z + ha.w * w[q].w;
            a1 += hb.x * w[q + 1].x + hb.y * w[q + 1].y + hb.z * w[q + 1].z + hb.w * w[q + 1].w;
            a2 += hc.x * w[q + 2].x + hc.y * w[q + 2].y + hc.z * w[q + 2].z + hc.w * w[q + 2].w;
            a3 += hd.x * w[q + 3].x + hd.y * w[q + 3].y + hd.z * w[q + 3].z + hd.w * w[q + 3].w;
          }
          pbase[(size_t)(tb + t) * ENC] = (a0 + a1) + (a2 + a3);
        }
      }
    }
    __syncthreads();
  }
  // ---- final chunk 127 ----
  if (wq > 0) {
    int buf = 127 & 1, tb = 127 * 16;
#pragma unroll 1
    for (int t = wq - 1; t < 16; t += 3) {
      const float4* hrow = (const float4*)(&hring[buf][t][0]);
      float a0 = pbias, a1 = 0.f, a2 = 0.f, a3 = 0.f;
#pragma unroll
      for (int q = 0; q < 16; q += 4) {
        float4 ha = hrow[q], hb = hrow[q + 1], hc = hrow[q + 2], hd = hrow[q + 3];
        a0 += ha.x * w[q].x + ha.y * w[q].y + ha.z * w[q].z + ha.w * w[q].w;
        a1 += hb.x * w[q + 1].x + hb.y * w[q + 1].y + hb.z * w[q + 1].z + hb.w * w[q + 1].w;
        a2 += hc.x * w[q + 2].x + hc.y * w[q + 2].y + hc.z * w[q + 2].z + hc.w * w[q + 2].w;
        a3 += hd.x * w[q + 3].x + hd.y * w[q + 3].y + hd.z * w[q + 3].z + hd.w * w[q + 3].w;
      }
      pbase[(size_t)(tb + t) * ENC] = (a0 + a1) + (a2 + a3);
    }
  }
}

extern "C" void kernel_launch(void* const* d_in, const int* in_sizes, int n_in,
                              void* d_out, int out_size, void* d_ws, size_t ws_size,
                              hipStream_t stream) {
  const float* x        = (const float*)d_in[0];
  const float* conv1_w  = (const float*)d_in[1];
  const float* conv1_b  = (const float*)d_in[2];
  const float* conv2_w  = (const float*)d_in[3];
  const float* conv2_b  = (const float*)d_in[4];
  const float* codebook = (const float*)d_in[5];
  const float* gru_w_ih = (const float*)d_in[6];
  const float* gru_w_hh = (const float*)d_in[7];
  const float* gru_b_ih = (const float*)d_in[8];
  const float* gru_b_hh = (const float*)d_in[9];
  const float* proj_w   = (const float*)d_in[10];
  const float* proj_b   = (const float*)d_in[11];

  float* out = (float*)d_out;
  float* quant = out + QOFF;     // quant_z output
  float* pred  = out + POFF;     // pred output
  float* codes_f = out + COFF;

  float* ws = (float*)d_ws;      // needs ~620 KB
  float* PC = ws + PCOFF;        // [128][192]
  int* codes_i = (int*)(ws + CIOFF);

  conv12q_kernel<<<2048, 256, 0, stream>>>(x, conv1_w, conv1_b, conv2_w, conv2_b,
                                           codebook, gru_w_ih, gru_b_ih, PC,
                                           quant, codes_f, codes_i);
  gruproj_kernel<<<64, 256, 0, stream>>>(PC, codes_i, gru_w_hh, gru_b_hh, proj_w, proj_b, pred);
}

// Round 13
// 1043.002 us; speedup vs baseline: 1.1211x; 1.1211x over previous
//
#include <hip/hip_runtime.h>

// Problem constants
#define NB   64      // batch
#define CIN  8
#define LIN  8192
#define L1N  4096    // conv1 out length
#define T2   2048    // conv2 out length (time steps)
#define ENC  64
#define NK   128     // codebook size
#define CD   64      // code dim
#define G3   192     // 3*ENC

// d_out layout (floats): quant_z [64*2048*64] | pred [64*2048*64] | codes [64*2048]
#define QOFF 0
#define POFF 8388608
#define COFF 16777216

// ws layout (floats): cnorm[128] @0 | PC[128*192] @128 | codes_i[131072] (int) @24704
#define PCOFF 128
#define CIOFF 24704

typedef _Float16 half2v __attribute__((ext_vector_type(2)));

__device__ __forceinline__ float sigf(float x) {
  float e = __builtin_amdgcn_exp2f(-1.4426950408889634f * x);
  return __builtin_amdgcn_rcpf(1.0f + e);
}
__device__ __forceinline__ float tanhf_fast(float x) {
  float e = __builtin_amdgcn_exp2f(2.8853900817779268f * x);
  return 1.0f - 2.0f * __builtin_amdgcn_rcpf(e + 1.0f);
}
__device__ __forceinline__ float rlane(float v, int k) {
  return __int_as_float(__builtin_amdgcn_readlane(__float_as_int(v), k));
}
__device__ __forceinline__ half2v as_h2(float v) { return __builtin_bit_cast(half2v, v); }

// ---------------- K0: prep = codebook norms (block 128) + PC table (blocks 0..127) ----------------
__global__ __launch_bounds__(192) void prep_kernel(const float* __restrict__ cb,
                                                   const float* __restrict__ w_ih,
                                                   const float* __restrict__ b_ih,
                                                   float* __restrict__ cnorm,
                                                   float* __restrict__ PC) {
  int blk = blockIdx.x;
  int j = threadIdx.x;
  if (blk == 128) {
    if (j < 128) {
      const float4* r = (const float4*)(cb + j * CD);
      float s0 = 0.f, s1 = 0.f, s2 = 0.f, s3 = 0.f;
#pragma unroll
      for (int q = 0; q < 16; q += 4) {
        float4 a = r[q], b = r[q + 1], cc = r[q + 2], d = r[q + 3];
        s0 += a.x * a.x + a.y * a.y + a.z * a.z + a.w * a.w;
        s1 += b.x * b.x + b.y * b.y + b.z * b.z + b.w * b.w;
        s2 += cc.x * cc.x + cc.y * cc.y + cc.z * cc.z + cc.w * cc.w;
        s3 += d.x * d.x + d.y * d.y + d.z * d.z + d.w * d.w;
      }
      cnorm[j] = (s0 + s1) + (s2 + s3);
    }
    return;
  }
  int c = blk;
  const float4* wp = (const float4*)(w_ih + j * ENC);
  const float4* cp = (const float4*)(cb + c * CD);
  float a0 = b_ih[j], a1 = 0.f, a2 = 0.f, a3 = 0.f;
#pragma unroll
  for (int q = 0; q < 16; q += 4) {
    float4 w0 = wp[q], c0 = cp[q];
    float4 w1 = wp[q + 1], c1 = cp[q + 1];
    float4 w2 = wp[q + 2], c2 = cp[q + 2];
    float4 w3 = wp[q + 3], c3 = cp[q + 3];
    a0 += w0.x * c0.x + w0.y * c0.y + w0.z * c0.z + w0.w * c0.w;
    a1 += w1.x * c1.x + w1.y * c1.y + w1.z * c1.z + w1.w * c1.w;
    a2 += w2.x * c2.x + w2.y * c2.y + w2.z * c2.z + w2.w * c2.w;
    a3 += w3.x * c3.x + w3.y * c3.y + w3.z * c3.z + w3.w * c3.w;
  }
  PC[c * G3 + j] = (a0 + a1) + (a2 + a3);
}

// ---------------- K1: FUSED conv1 + relu + conv2 + relu + VQ argmin + gather (R10, proven) ----------------
__global__ __launch_bounds__(256) void conv12q_kernel(const float* __restrict__ x,
                                                      const float* __restrict__ w1,
                                                      const float* __restrict__ b1,
                                                      const float* __restrict__ w2,
                                                      const float* __restrict__ b2,
                                                      const float* __restrict__ cb,
                                                      const float* __restrict__ cnorm,
                                                      float* __restrict__ quant,
                                                      float* __restrict__ codes_f,
                                                      int* __restrict__ codes_i) {
  __shared__ float sw2[32 * 5 * 64];     // 40960 B
  __shared__ float sw1[1280];            //  5120 B
  __shared__ float sy[32][136];          // 17408 B
  __shared__ float ubuf[4096];           // 16384 B : sxx[8][280] (phase A/B) then sz[64][64]
  float (*sxx)[280] = (float(*)[280])ubuf;
  float (*sz)[64]   = (float(*)[64])ubuf;
  int b = blockIdx.x >> 5;
  int t0 = (blockIdx.x & 31) * 64;
  int tid = threadIdx.x;

  // ---- phase A: stage x-tile + conv1 weights + conv2 weights ----
  for (int i = tid; i < 32 * 5 * 64; i += 256) {
    int co = i & 63, r = i >> 6;
    sw2[i] = w2[co * 160 + r];
  }
  for (int i = tid; i < 1280; i += 256) sw1[i] = w1[i];
  {
    const float* xb = x + b * CIN * LIN;
    int X0 = 4 * t0 - 10;
    for (int i = tid; i < 8 * 280; i += 256) {
      int ci = i / 280, xo = i - ci * 280;
      int xi = X0 + xo;
      sxx[ci][xo] = ((unsigned)xi < (unsigned)LIN) ? xb[ci * LIN + xi] : 0.f;
    }
  }
  __syncthreads();

  // ---- phase B: y1 window (conv1+relu), conv1's accumulation order (bias, ci, k) ----
  {
    int co1 = tid >> 3, sub = tid & 7;       // co1 in [0,32), 17 outputs per thread
    float acc1[17];
    float bias = b1[co1];
#pragma unroll
    for (int jj = 0; jj < 17; jj++) acc1[jj] = bias;
#pragma unroll 1
    for (int ci = 0; ci < 8; ci++) {
      float xv[38];
      const float2* s2 = (const float2*)(&sxx[ci][34 * sub]);
#pragma unroll
      for (int q = 0; q < 19; q++) {
        float2 v = s2[q];
        xv[2 * q] = v.x; xv[2 * q + 1] = v.y;
      }
      float wk1[5];
#pragma unroll
      for (int k = 0; k < 5; k++) wk1[k] = sw1[(co1 * 8 + ci) * 5 + k];
#pragma unroll
      for (int jj = 0; jj < 17; jj++) {
#pragma unroll
        for (int k = 0; k < 5; k++) acc1[jj] = fmaf(xv[2 * jj + k], wk1[k], acc1[jj]);
      }
    }
#pragma unroll
    for (int jj = 0; jj < 17; jj++) {
      int u = 17 * sub + jj;
      int p = 2 * t0 - 4 + u;                // y1 position
      sy[co1][u] = ((unsigned)p < (unsigned)L1N) ? fmaxf(acc1[jj], 0.f) : 0.f;
    }
  }
  __syncthreads();                            // sxx dead from here; ubuf becomes sz

  // ---- phase C: conv2 + relu into sz ----
  int co = tid & 63, ts = tid >> 6;
  {
    float acc[16];
    float bb = b2[co];
#pragma unroll
    for (int i = 0; i < 16; i++) acc[i] = bb;
    for (int ci = 0; ci < 32; ci++) {
      float xr[40];
      const float4* sx4 = (const float4*)(&sy[ci][32 * ts]);
#pragma unroll
      for (int q = 0; q < 10; q++) {
        float4 v = sx4[q];
        xr[4 * q] = v.x; xr[4 * q + 1] = v.y; xr[4 * q + 2] = v.z; xr[4 * q + 3] = v.w;
      }
      float wk[5];
#pragma unroll
      for (int k = 0; k < 5; k++) wk[k] = sw2[(ci * 5 + k) * 64 + co];
#pragma unroll
      for (int i = 0; i < 16; i++) {
#pragma unroll
        for (int k = 0; k < 5; k++) acc[i] = fmaf(xr[2 * i + k + 2], wk[k], acc[i]);
      }
    }
#pragma unroll
    for (int i = 0; i < 16; i++) sz[ts * 16 + i][co] = fmaxf(acc[i], 0.f);
  }
  __syncthreads();

  // ---- quant phase ----
  int lane = co, wave = ts;
  float4 ca[16], cq[16];
  {
    const float4* pa = (const float4*)(cb + lane * CD);
    const float4* pb = (const float4*)(cb + (64 + lane) * CD);
#pragma unroll
    for (int q = 0; q < 16; q++) { ca[q] = pa[q]; cq[q] = pb[q]; }
  }
  float cn0 = cnorm[lane], cn1 = cnorm[64 + lane];
  int vg0 = b * T2 + t0 + wave * 16;
  for (int i = 0; i < 16; i++) {
    int vl = wave * 16 + i;
    int v = vg0 + i;
    float d00 = 0.f, d01 = 0.f, d02 = 0.f, d03 = 0.f;
    float d10 = 0.f, d11 = 0.f, d12 = 0.f, d13 = 0.f;
#pragma unroll
    for (int q = 0; q < 16; q++) {
      float4 zq = *(const float4*)(&sz[vl][4 * q]);   // broadcast read, conflict-free
      d00 = fmaf(ca[q].x, zq.x, d00); d01 = fmaf(ca[q].y, zq.y, d01);
      d02 = fmaf(ca[q].z, zq.z, d02); d03 = fmaf(ca[q].w, zq.w, d03);
      d10 = fmaf(cq[q].x, zq.x, d10); d11 = fmaf(cq[q].y, zq.y, d11);
      d12 = fmaf(cq[q].z, zq.z, d12); d13 = fmaf(cq[q].w, zq.w, d13);
    }
    float s0 = cn0 - 2.f * ((d00 + d01) + (d02 + d03));
    float s1 = cn1 - 2.f * ((d10 + d11) + (d12 + d13));
    float sc; int idx;
    if (s1 < s0) { sc = s1; idx = 64 + lane; } else { sc = s0; idx = lane; }
#pragma unroll
    for (int m = 1; m < 64; m <<= 1) {
      float os = __shfl_xor(sc, m);
      int oi = __shfl_xor(idx, m);
      if (os < sc || (os == sc && oi < idx)) { sc = os; idx = oi; }
    }
    if (lane == 0) { codes_f[v] = (float)idx; codes_i[v] = idx; }
    quant[v * 64 + lane] = cb[idx * 64 + lane];
  }
}

// ---------------- K5: FUSED GRU scan + projection + wave-1 x-gather (R11, proven 755us) ----------------
__global__ __attribute__((amdgpu_flat_work_group_size(256, 256), amdgpu_waves_per_eu(1, 1)))
void gruproj_kernel(const float* __restrict__ PC,
                    const int* __restrict__ codes_i,
                    const float* __restrict__ w_hh,
                    const float* __restrict__ b_hh,
                    const float* __restrict__ proj_w,
                    const float* __restrict__ proj_b,
                    float* __restrict__ pred) {
  __shared__ float pcl[NK * G3];         // 98304 B
  __shared__ int   cpl[T2];              //  8192 B
  __shared__ float hring[2][16][64];     //  8192 B
  __shared__ float xring[2][16][3][64];  // 24576 B  (total 139264 B)
  int b = blockIdx.x;
  int tid = threadIdx.x;
  int lane = tid & 63;
  int wq = tid >> 6;

  // stage this batch's codes + the PC table with all 256 threads
  {
    const int4* src = (const int4*)(codes_i + b * T2);
    int4* dst = (int4*)cpl;
    for (int f = tid; f < T2 / 4; f += 256) dst[f] = src[f];
    const float4* s2 = (const float4*)PC;
    float4* d2 = (float4*)pcl;
    for (int f = tid; f < NK * G3 / 4; f += 256) d2[f] = s2[f];
  }
  __syncthreads();

  // ---- per-role setup (wave-uniform branch) ----
  half2v wr[32], wz[32], wn[32];
  float br = 0.f, bz = 0.f, bn = 0.f;
  float hreg = 0.f;
  float4 w[16];
  float pbias = 0.f;

  if (wq == 0) {
    const float2* p0 = (const float2*)(w_hh + lane * ENC);
    const float2* p1 = (const float2*)(w_hh + (64 + lane) * ENC);
    const float2* p2 = (const float2*)(w_hh + (128 + lane) * ENC);
#pragma unroll
    for (int m = 0; m < 32; m++) {
      float2 a = p0[m]; wr[m] = (half2v){(_Float16)a.x, (_Float16)a.y};
      float2 c = p1[m]; wz[m] = (half2v){(_Float16)c.x, (_Float16)c.y};
      float2 d = p2[m]; wn[m] = (half2v){(_Float16)d.x, (_Float16)d.y};
    }
    br = b_hh[lane]; bz = b_hh[64 + lane]; bn = b_hh[128 + lane];
  } else {
    const float4* wp = (const float4*)(proj_w + lane * ENC);
#pragma unroll
    for (int q = 0; q < 16; q++) w[q] = wp[q];
    pbias = proj_b[lane];
    if (wq == 1) {
      // prologue: gather x rows for chunk 0 into xring[0]
#pragma unroll 1
      for (int i = 0; i < 16; i++) {
        int code = cpl[i];
        const float* g = pcl + code * G3;
        xring[0][i][0][lane] = g[lane];
        xring[0][i][1][lane] = g[64 + lane];
        xring[0][i][2][lane] = g[128 + lane];
      }
    }
  }
  __syncthreads();   // xring[0] ready for wave 0

  int lane2a = 2 * lane, lane2b = 2 * lane + 1;  // shuffle sources (loop-invariant)
  float* pbase = pred + (size_t)b * T2 * ENC + lane;

#pragma unroll 1
  for (int c = 0; c < 128; c++) {
    if (wq == 0) {
      // ---- 16 GRU steps using xring[c&1], writing h into hring[c&1] ----
      const float* xbuf = &xring[c & 1][0][0][0];
#pragma unroll 1
      for (int i = 0; i < 16; i++) {
        const float* xp = xbuf + i * 192;
        float xr = xp[lane], xz = xp[64 + lane], xn = xp[128 + lane];
        float he = __shfl(hreg, lane2a);
        float ho = __shfl(hreg, lane2b);
        half2v hp2 = {(_Float16)he, (_Float16)ho};
        float hpk = __builtin_bit_cast(float, hp2);
        float fr0 = br, fr1 = 0.f, fr2 = 0.f, fr3 = 0.f;
        float fz0 = bz, fz1 = 0.f, fz2 = 0.f, fz3 = 0.f;
        float fn0 = bn, fn1 = 0.f, fn2 = 0.f, fn3 = 0.f;
#define MV(q) { \
    float s0 = rlane(hpk, 4 * (q) + 0); float s1 = rlane(hpk, 4 * (q) + 1); \
    float s2 = rlane(hpk, 4 * (q) + 2); float s3 = rlane(hpk, 4 * (q) + 3); \
    fr0 = __builtin_amdgcn_fdot2(wr[4 * (q) + 0], as_h2(s0), fr0, false); \
    fr1 = __builtin_amdgcn_fdot2(wr[4 * (q) + 1], as_h2(s1), fr1, false); \
    fr2 = __builtin_amdgcn_fdot2(wr[4 * (q) + 2], as_h2(s2), fr2, false); \
    fr3 = __builtin_amdgcn_fdot2(wr[4 * (q) + 3], as_h2(s3), fr3, false); \
    fz0 = __builtin_amdgcn_fdot2(wz[4 * (q) + 0], as_h2(s0), fz0, false); \
    fz1 = __builtin_amdgcn_fdot2(wz[4 * (q) + 1], as_h2(s1), fz1, false); \
    fz2 = __builtin_amdgcn_fdot2(wz[4 * (q) + 2], as_h2(s2), fz2, false); \
    fz3 = __builtin_amdgcn_fdot2(wz[4 * (q) + 3], as_h2(s3), fz3, false); \
    fn0 = __builtin_amdgcn_fdot2(wn[4 * (q) + 0], as_h2(s0), fn0, false); \
    fn1 = __builtin_amdgcn_fdot2(wn[4 * (q) + 1], as_h2(s1), fn1, false); \
    fn2 = __builtin_amdgcn_fdot2(wn[4 * (q) + 2], as_h2(s2), fn2, false); \
    fn3 = __builtin_amdgcn_fdot2(wn[4 * (q) + 3], as_h2(s3), fn3, false); }
        MV(0) MV(1) MV(2) MV(3) MV(4) MV(5) MV(6) MV(7)
#undef MV
        float ghr = (fr0 + fr1) + (fr2 + fr3);
        float ghz = (fz0 + fz1) + (fz2 + fz3);
        float ghn = (fn0 + fn1) + (fn2 + fn3);
        float r = sigf(xr + ghr);
        float zg = sigf(xz + ghz);
        float n = tanhf_fast(xn + r * ghn);
        hreg = fmaf(zg, hreg - n, n);
        hring[c & 1][i][lane] = hreg;
      }
    } else {
      if (wq == 1 && c < 127) {
        // ---- gather x rows for chunk c+1 into xring[(c+1)&1] ----
        int tbase = (c + 1) * 16;
        float* xb2 = &xring[(c + 1) & 1][0][0][0];
#pragma unroll 1
        for (int i = 0; i < 16; i++) {
          int code = cpl[tbase + i];
          const float* g = pcl + code * G3;
          float* xo = xb2 + i * 192;
          xo[lane] = g[lane];
          xo[64 + lane] = g[64 + lane];
          xo[128 + lane] = g[128 + lane];
        }
      }
      if (c > 0) {
        // ---- project chunk c-1 from hring[(c-1)&1] ----
        int cc = c - 1, buf = cc & 1, tb = cc * 16;
#pragma unroll 1
        for (int t = wq - 1; t < 16; t += 3) {
          const float4* hrow = (const float4*)(&hring[buf][t][0]);   // broadcast reads
          float a0 = pbias, a1 = 0.f, a2 = 0.f, a3 = 0.f;
#pragma unroll
          for (int q = 0; q < 16; q += 4) {
            float4 ha = hrow[q], hb = hrow[q + 1], hc = hrow[q + 2], hd = hrow[q + 3];
            a0 += ha.x * w[q].x + ha.y * w[q].y + ha.z * w[q].z + ha.w * w[q].w;
            a1 += hb.x * w[q + 1].x + hb.y * w[q + 1].y + hb.z * w[q + 1].z + hb.w * w[q + 1].w;
            a2 += hc.x * w[q + 2].x + hc.y * w[q + 2].y + hc.z * w[q + 2].z + hc.w * w[q + 2].w;
            a3 += hd.x * w[q + 3].x + hd.y * w[q + 3].y + hd.z * w[q + 3].z + hd.w * w[q + 3].w;
          }
          pbase[(size_t)(tb + t) * ENC] = (a0 + a1) + (a2 + a3);
        }
      }
    }
    __syncthreads();
  }
  // ---- final chunk 127 ----
  if (wq > 0) {
    int buf = 127 & 1, tb = 127 * 16;
#pragma unroll 1
    for (int t = wq - 1; t < 16; t += 3) {
      const float4* hrow = (const float4*)(&hring[buf][t][0]);
      float a0 = pbias, a1 = 0.f, a2 = 0.f, a3 = 0.f;
#pragma unroll
      for (int q = 0; q < 16; q += 4) {
        float4 ha = hrow[q], hb = hrow[q + 1], hc = hrow[q + 2], hd = hrow[q + 3];
        a0 += ha.x * w[q].x + ha.y * w[q].y + ha.z * w[q].z + ha.w * w[q].w;
        a1 += hb.x * w[q + 1].x + hb.y * w[q + 1].y + hb.z * w[q + 1].z + hb.w * w[q + 1].w;
        a2 += hc.x * w[q + 2].x + hc.y * w[q + 2].y + hc.z * w[q + 2].z + hc.w * w[q + 2].w;
        a3 += hd.x * w[q + 3].x + hd.y * w[q + 3].y + hd.z * w[q + 3].z + hd.w * w[q + 3].w;
      }
      pbase[(size_t)(tb + t) * ENC] = (a0 + a1) + (a2 + a3);
    }
  }
}

extern "C" void kernel_launch(void* const* d_in, const int* in_sizes, int n_in,
                              void* d_out, int out_size, void* d_ws, size_t ws_size,
                              hipStream_t stream) {
  const float* x        = (const float*)d_in[0];
  const float* conv1_w  = (const float*)d_in[1];
  const float* conv1_b  = (const float*)d_in[2];
  const float* conv2_w  = (const float*)d_in[3];
  const float* conv2_b  = (const float*)d_in[4];
  const float* codebook = (const float*)d_in[5];
  const float* gru_w_ih = (const float*)d_in[6];
  const float* gru_w_hh = (const float*)d_in[7];
  const float* gru_b_ih = (const float*)d_in[8];
  const float* gru_b_hh = (const float*)d_in[9];
  const float* proj_w   = (const float*)d_in[10];
  const float* proj_b   = (const float*)d_in[11];

  float* out = (float*)d_out;
  float* quant = out + QOFF;     // quant_z output
  float* pred  = out + POFF;     // pred output
  float* codes_f = out + COFF;

  float* ws = (float*)d_ws;      // needs ~620 KB
  float* cnorm = ws;
  float* PC = ws + PCOFF;        // [128][192]
  int* codes_i = (int*)(ws + CIOFF);

  prep_kernel<<<129, 192, 0, stream>>>(codebook, gru_w_ih, gru_b_ih, cnorm, PC);
  conv12q_kernel<<<2048, 256, 0, stream>>>(x, conv1_w, conv1_b, conv2_w, conv2_b,
                                           codebook, cnorm, quant, codes_f, codes_i);
  gruproj_kernel<<<64, 256, 0, stream>>>(PC, codes_i, gru_w_hh, gru_b_hh, proj_w, proj_b, pred);
}